// Round 1
// baseline (185.381 us; speedup 1.0000x reference)
//
#include <hip/hip_runtime.h>
#include <stdint.h>

#define NROWS 8192
#define DDIM  128
#define PPART 8
#define JT_PER_PART ((NROWS/16)/PPART)   // 64 column tiles per partition

typedef __bf16 bf16x8 __attribute__((ext_vector_type(8)));
typedef float  f32x4  __attribute__((ext_vector_type(4)));

__device__ __forceinline__ unsigned short f2bf_rne(float f) {
    union { float f; uint32_t u; } v; v.f = f;
    uint32_t r = (v.u + 0x7FFFu + ((v.u >> 16) & 1u)) >> 16;
    return (unsigned short)r;
}

// Kernel 1: fp32 -> bf16 (ts pre-scaled by 1/T = 100), zero the accumulator.
__global__ void convert_kernel(const float* __restrict__ ts, const float* __restrict__ nt,
                               unsigned short* __restrict__ ts_bf,
                               unsigned short* __restrict__ nt_bf,
                               float* __restrict__ acc) {
    const int nvec = (NROWS * DDIM) / 4;          // 262144 float4 per matrix
    int tid = blockIdx.x * blockDim.x + threadIdx.x; // 0 .. 2*nvec-1
    bool isNT = tid >= nvec;
    int i = isNT ? (tid - nvec) : tid;
    const float4 v = ((const float4*)(isNT ? nt : ts))[i];
    float sc = isNT ? 1.0f : 100.0f;
    ushort4 o;
    o.x = f2bf_rne(v.x * sc); o.y = f2bf_rne(v.y * sc);
    o.z = f2bf_rne(v.z * sc); o.w = f2bf_rne(v.w * sc);
    ((ushort4*)(isNT ? nt_bf : ts_bf))[i] = o;
    if (tid == 0) *acc = 0.0f;
}

// Kernel 2: per-row online-softmax stats over a column partition.
// 1 wave per block. Wave owns 32 rows = two 16-row MFMA strips.
// grid = (NROWS/32, PPART, 2 directions)
__global__ __launch_bounds__(64) void rowstats_kernel(
        const unsigned short* __restrict__ ts_bf,
        const unsigned short* __restrict__ nt_bf,
        float* __restrict__ pm, float* __restrict__ ps, float* __restrict__ pd) {
    const int lane = threadIdx.x;
    const int c    = lane & 15;      // col within tile (C/D), row of A/B operand
    const int quad = lane >> 4;      // k-chunk selector for operands, row-quad for C/D
    const int rows0 = blockIdx.x * 32;
    const int part  = blockIdx.y;
    const int dir   = blockIdx.z;

    const unsigned short* A = dir ? nt_bf : ts_bf;
    const unsigned short* B = dir ? ts_bf : nt_bf;

    // A fragments for both strips, all 4 K-chunks (K=128 = 4 x 32). Held in regs.
    bf16x8 a[2][4];
#pragma unroll
    for (int s = 0; s < 2; ++s) {
        const unsigned short* abase = A + (rows0 + s * 16 + c) * DDIM + quad * 8;
#pragma unroll
        for (int kc = 0; kc < 4; ++kc)
            a[s][kc] = *(const bf16x8*)(abase + kc * 32);
    }

    float m[2][4], ss[2][4], dg[2][4];
#pragma unroll
    for (int s = 0; s < 2; ++s)
#pragma unroll
        for (int r = 0; r < 4; ++r) { m[s][r] = -INFINITY; ss[s][r] = 0.0f; dg[s][r] = 0.0f; }

    const int jt0 = part * JT_PER_PART;
    for (int jt = jt0; jt < jt0 + JT_PER_PART; ++jt) {
        const int j0 = jt * 16;
        bf16x8 b[4];
        const unsigned short* bbase = B + (j0 + c) * DDIM + quad * 8;
#pragma unroll
        for (int kc = 0; kc < 4; ++kc)
            b[kc] = *(const bf16x8*)(bbase + kc * 32);

        f32x4 acc0 = {0.f, 0.f, 0.f, 0.f};
        f32x4 acc1 = {0.f, 0.f, 0.f, 0.f};
#pragma unroll
        for (int kc = 0; kc < 4; ++kc) {
            acc0 = __builtin_amdgcn_mfma_f32_16x16x32_bf16(a[0][kc], b[kc], acc0, 0, 0, 0);
            acc1 = __builtin_amdgcn_mfma_f32_16x16x32_bf16(a[1][kc], b[kc], acc1, 0, 0, 0);
        }

#pragma unroll
        for (int s = 0; s < 2; ++s) {
            const f32x4 av = s ? acc1 : acc0;
            const bool diagTile = (j0 == rows0 + s * 16);  // wave-uniform
#pragma unroll
            for (int r = 0; r < 4; ++r) {
                float x = av[r];   // logits already scaled: ts was pre-multiplied by 100
                if (diagTile) {
                    if (c == quad * 4 + r) dg[s][r] += x;  // keep + record diagonal
                    else x = -1.0e6f;                      // MASK_VAL / TEMPERATURE
                }
                float mn = fmaxf(m[s][r], x);
                ss[s][r] = ss[s][r] * __expf(m[s][r] - mn) + __expf(x - mn);
                m[s][r] = mn;
            }
        }
    }

    // Combine across the 16 lanes of each quad (they share the same 4 rows).
#pragma unroll
    for (int s = 0; s < 2; ++s) {
#pragma unroll
        for (int r = 0; r < 4; ++r) {
            float mm = m[s][r], sv = ss[s][r], dd = dg[s][r];
#pragma unroll
            for (int off = 1; off < 16; off <<= 1) {
                float m2 = __shfl_xor(mm, off, 64);
                float s2 = __shfl_xor(sv, off, 64);
                float d2 = __shfl_xor(dd, off, 64);
                float mn = fmaxf(mm, m2);
                sv = sv * __expf(mm - mn) + s2 * __expf(m2 - mn);
                mm = mn;
                dd += d2;
            }
            if (c == 0) {
                int row = rows0 + s * 16 + quad * 4 + r;
                int idx = (dir * NROWS + row) * PPART + part;
                pm[idx] = mm; ps[idx] = sv; pd[idx] = dd;
            }
        }
    }
}

// Kernel 3: merge partitions per (dir,row), compute lsm_ii, reduce, atomicAdd.
__global__ void merge_kernel(const float* __restrict__ pm, const float* __restrict__ ps,
                             const float* __restrict__ pd, float* __restrict__ acc) {
    int tid = blockIdx.x * blockDim.x + threadIdx.x;  // 0 .. 2*NROWS-1
    const float* pmr = pm + tid * PPART;
    const float* psr = ps + tid * PPART;
    const float* pdr = pd + tid * PPART;
    float mt = -INFINITY;
#pragma unroll
    for (int p = 0; p < PPART; ++p) mt = fmaxf(mt, pmr[p]);
    float st = 0.0f, dt = 0.0f;
#pragma unroll
    for (int p = 0; p < PPART; ++p) {
        st += psr[p] * __expf(pmr[p] - mt);
        dt += pdr[p];
    }
    float lsm = dt - mt - __logf(st);

    // block reduction (256 threads = 4 waves)
    float v = lsm;
#pragma unroll
    for (int off = 32; off; off >>= 1) v += __shfl_down(v, off, 64);
    __shared__ float wsum[4];
    if ((threadIdx.x & 63) == 0) wsum[threadIdx.x >> 6] = v;
    __syncthreads();
    if (threadIdx.x == 0)
        atomicAdd(acc, wsum[0] + wsum[1] + wsum[2] + wsum[3]);
}

// Kernel 4: finalize  total = -(sum lsm)/(2N), nan/inf -> 0
__global__ void final_kernel(const float* __restrict__ acc, float* __restrict__ out) {
    float t = -(*acc) / (2.0f * NROWS);
    if (!isfinite(t)) t = 0.0f;
    out[0] = t;
}

extern "C" void kernel_launch(void* const* d_in, const int* in_sizes, int n_in,
                              void* d_out, int out_size, void* d_ws, size_t ws_size,
                              hipStream_t stream) {
    const float* ts = (const float*)d_in[0];
    const float* nt = (const float*)d_in[1];
    float* out = (float*)d_out;

    // workspace layout
    unsigned short* ts_bf = (unsigned short*)d_ws;                 // 2 MB
    unsigned short* nt_bf = ts_bf + NROWS * DDIM;                  // 2 MB
    float* pm = (float*)(nt_bf + NROWS * DDIM);                    // 512 KB
    float* ps = pm + 2 * NROWS * PPART;                            // 512 KB
    float* pd = ps + 2 * NROWS * PPART;                            // 512 KB
    float* acc = pd + 2 * NROWS * PPART;                           // 4 B

    // (1) convert: 2 * 262144 float4 elements / 256 threads = 2048 blocks
    convert_kernel<<<2048, 256, 0, stream>>>(ts, nt, ts_bf, nt_bf, acc);
    // (2) row stats: 256 row-groups x 8 partitions x 2 directions, 1 wave each
    rowstats_kernel<<<dim3(NROWS / 32, PPART, 2), 64, 0, stream>>>(ts_bf, nt_bf, pm, ps, pd);
    // (3) merge: 2*NROWS threads
    merge_kernel<<<(2 * NROWS) / 256, 256, 0, stream>>>(pm, ps, pd, acc);
    // (4) finalize
    final_kernel<<<1, 1, 0, stream>>>(acc, out);
}